// Round 1
// baseline (10044.714 us; speedup 1.0000x reference)
//
#include <hip/hip_runtime.h>
#include <hip/hip_bf16.h>
#include <math.h>

#define B_ 128
#define T_ 256
#define F_ 64
#define H_ 512
#define G4_ 2048

typedef __attribute__((ext_vector_type(8))) short bf16x8;
typedef __attribute__((ext_vector_type(4))) float f32x4;

__device__ __forceinline__ float sigmoidf_(float x) { return 1.f / (1.f + expf(-x)); }

// ---- transpose+cast four [512,2048] fp32 weight mats -> [2048,512] bf16 ----
__global__ __launch_bounds__(256) void transpose_cast_k(
    const float* __restrict__ s0, const float* __restrict__ s1,
    const float* __restrict__ s2, const float* __restrict__ s3,
    __hip_bfloat16* __restrict__ dst)
{
  __shared__ float lds[64][65];
  const float* src = (blockIdx.z == 0) ? s0 : (blockIdx.z == 1) ? s1 : (blockIdx.z == 2) ? s2 : s3;
  __hip_bfloat16* d = dst + (size_t)blockIdx.z * (G4_ * H_);
  int n0 = blockIdx.x * 64, k0 = blockIdx.y * 64;
  int tx = threadIdx.x & 63, ty = threadIdx.x >> 6;
#pragma unroll
  for (int r = 0; r < 16; r++) { int k = r * 4 + ty; lds[k][tx] = src[(size_t)(k0 + k) * G4_ + n0 + tx]; }
  __syncthreads();
#pragma unroll
  for (int r = 0; r < 16; r++) { int n = r * 4 + ty; d[(size_t)(n0 + n) * H_ + k0 + tx] = __float2bfloat16(lds[tx][n]); }
}

// ---- cast W1 to bf16 + zero state buffers ----
__global__ void prep_misc_k(const float* __restrict__ w1, __hip_bfloat16* __restrict__ w1b,
                            float* __restrict__ zbase, int nzero)
{
  int i = blockIdx.x * blockDim.x + threadIdx.x;
  int stride = gridDim.x * blockDim.x;
  for (int k = i; k < F_ * H_; k += stride) w1b[k] = __float2bfloat16(w1[k]);
  for (int k = i; k < nzero; k += stride) zbase[k] = 0.f;
}

// ---- dense1 + spectral-norm row normalization; h0 out as bf16 [B*T, H] ----
__global__ __launch_bounds__(512) void dense1_k(
    const float* __restrict__ x, const __hip_bfloat16* __restrict__ w1b,
    const float* __restrict__ b1, __hip_bfloat16* __restrict__ h0)
{
  __shared__ float red[8];
  int j = threadIdx.x;
  int wave = j >> 6, lane = j & 63;
  float wcol[64];
#pragma unroll
  for (int k = 0; k < 64; k++) wcol[k] = __bfloat162float(w1b[k * H_ + j]);
  float bj = b1[j];
  for (int r = 0; r < 32; r++) {
    int row = blockIdx.x * 32 + r;
    const float* xr = x + (size_t)row * F_;
    float acc = bj;
#pragma unroll
    for (int k = 0; k < 64; k++) acc += xr[k] * wcol[k];
    float ss = acc * acc;
#pragma unroll
    for (int o = 32; o; o >>= 1) ss += __shfl_down(ss, o);
    if (lane == 0) red[wave] = ss;
    __syncthreads();
    float tot = red[0] + red[1] + red[2] + red[3] + red[4] + red[5] + red[6] + red[7];
    float sc = sqrtf(512.f) / fmaxf(sqrtf(tot), 1e-12f);
    h0[(size_t)row * H_ + j] = __float2bfloat16(acc * sc);
    __syncthreads();
  }
}

// ---- one LSTM time step: 64 blocks = 4 batch-strips x 16 unit-strips ----
// wave w computes gate w for its (32 batch x 32 unit) tile, K=1024 fused.
__global__ __launch_bounds__(256) void lstm_step_k(
    const __hip_bfloat16* __restrict__ hin,    // [B, H] bf16 (prev h)
    const __hip_bfloat16* __restrict__ xsrc,   // [B*T, H] bf16 (x contributions)
    const __hip_bfloat16* __restrict__ Wht,    // [2048, 512] bf16 (transposed)
    const __hip_bfloat16* __restrict__ Wxt,    // [2048, 512] bf16 (transposed)
    const float* __restrict__ bias,            // [2048]
    float* __restrict__ c,                     // [B, H] fp32
    __hip_bfloat16* __restrict__ hout,         // [B, H] bf16
    __hip_bfloat16* __restrict__ seqout,       // [B*T, H] bf16 or null
    float* __restrict__ hf32,                  // [B, H] fp32 or null
    int t)
{
  const int tid = threadIdx.x;
  const int wave = tid >> 6;
  const int lane = tid & 63;
  const int lr = lane & 15;   // m (A) / n (B) within 16-tile
  const int lk = lane >> 4;   // k-octet quad
  const int bb = blockIdx.x & 3;
  const int bu = blockIdx.x >> 2;
  const int m0 = bb * 32;
  const int u0 = bu * 32;
  const int gbase = wave * H_ + u0;   // this wave's gate-column base

  f32x4 acc00 = {0.f, 0.f, 0.f, 0.f}, acc01 = {0.f, 0.f, 0.f, 0.f};
  f32x4 acc10 = {0.f, 0.f, 0.f, 0.f}, acc11 = {0.f, 0.f, 0.f, 0.f};

  // K-loop 1: h_prev @ Wh
  {
    const __hip_bfloat16* a0p = hin + (size_t)(m0 + lr) * H_ + lk * 8;
    const __hip_bfloat16* a1p = a0p + 16 * H_;
    const __hip_bfloat16* b0p = Wht + (size_t)(gbase + lr) * H_ + lk * 8;
    const __hip_bfloat16* b1p = b0p + 16 * H_;
#pragma unroll 4
    for (int kc = 0; kc < H_; kc += 32) {
      bf16x8 a0 = *(const bf16x8*)(a0p + kc);
      bf16x8 a1 = *(const bf16x8*)(a1p + kc);
      bf16x8 b0 = *(const bf16x8*)(b0p + kc);
      bf16x8 b1 = *(const bf16x8*)(b1p + kc);
      acc00 = __builtin_amdgcn_mfma_f32_16x16x32_bf16(a0, b0, acc00, 0, 0, 0);
      acc01 = __builtin_amdgcn_mfma_f32_16x16x32_bf16(a0, b1, acc01, 0, 0, 0);
      acc10 = __builtin_amdgcn_mfma_f32_16x16x32_bf16(a1, b0, acc10, 0, 0, 0);
      acc11 = __builtin_amdgcn_mfma_f32_16x16x32_bf16(a1, b1, acc11, 0, 0, 0);
    }
  }
  // K-loop 2: x_t @ Wx  (x rows live at (b*T + t))
  {
    const __hip_bfloat16* a0p = xsrc + ((size_t)(m0 + lr) * T_ + t) * H_ + lk * 8;
    const __hip_bfloat16* a1p = xsrc + ((size_t)(m0 + 16 + lr) * T_ + t) * H_ + lk * 8;
    const __hip_bfloat16* b0p = Wxt + (size_t)(gbase + lr) * H_ + lk * 8;
    const __hip_bfloat16* b1p = b0p + 16 * H_;
#pragma unroll 4
    for (int kc = 0; kc < H_; kc += 32) {
      bf16x8 a0 = *(const bf16x8*)(a0p + kc);
      bf16x8 a1 = *(const bf16x8*)(a1p + kc);
      bf16x8 b0 = *(const bf16x8*)(b0p + kc);
      bf16x8 b1 = *(const bf16x8*)(b1p + kc);
      acc00 = __builtin_amdgcn_mfma_f32_16x16x32_bf16(a0, b0, acc00, 0, 0, 0);
      acc01 = __builtin_amdgcn_mfma_f32_16x16x32_bf16(a0, b1, acc01, 0, 0, 0);
      acc10 = __builtin_amdgcn_mfma_f32_16x16x32_bf16(a1, b0, acc10, 0, 0, 0);
      acc11 = __builtin_amdgcn_mfma_f32_16x16x32_bf16(a1, b1, acc11, 0, 0, 0);
    }
  }

  // stage pre-activation gates in LDS: g[gate][m][u]
  __shared__ float g[4][32][33];
  float bias0 = bias[gbase + lr];
  float bias1 = bias[gbase + 16 + lr];
#pragma unroll
  for (int r = 0; r < 4; r++) {
    // C/D layout: col = lane&15, row = (lane>>4)*4 + r
    g[wave][lk * 4 + r][lr]           = acc00[r] + bias0;
    g[wave][lk * 4 + r][16 + lr]      = acc01[r] + bias1;
    g[wave][16 + lk * 4 + r][lr]      = acc10[r] + bias0;
    g[wave][16 + lk * 4 + r][16 + lr] = acc11[r] + bias1;
  }
  __syncthreads();

  for (int e = tid; e < 1024; e += 256) {
    int m = e >> 5, u = e & 31;
    float iv = sigmoidf_(g[0][m][u]);
    float fv = sigmoidf_(g[1][m][u]);
    float cb = tanhf(g[2][m][u]);
    float ov = sigmoidf_(g[3][m][u]);
    int gi = (m0 + m) * H_ + u0 + u;
    float cn = fv * c[gi] + iv * cb;
    c[gi] = cn;
    float hv = ov * tanhf(cn);
    __hip_bfloat16 hb = __float2bfloat16(hv);
    hout[gi] = hb;
    if (seqout) seqout[((size_t)(m0 + m) * T_ + t) * H_ + u0 + u] = hb;
    if (hf32) hf32[gi] = hv;
  }
}

// ---- LayerNorm + dense2(relu) + dense3; one block per batch row ----
__global__ __launch_bounds__(256) void final_k(
    const float* __restrict__ h2, const float* __restrict__ gamma, const float* __restrict__ beta,
    const float* __restrict__ W2, const float* __restrict__ b2,
    const float* __restrict__ W3, const float* __restrict__ b3, float* __restrict__ out)
{
  __shared__ float y[512];
  __shared__ float redS[4], redQ[4], redP[4];
  int b = blockIdx.x, tid = threadIdx.x;
  int wave = tid >> 6, lane = tid & 63;
  float v0 = h2[b * H_ + tid], v1 = h2[b * H_ + 256 + tid];
  float s = v0 + v1, q = v0 * v0 + v1 * v1;
#pragma unroll
  for (int o = 32; o; o >>= 1) { s += __shfl_down(s, o); q += __shfl_down(q, o); }
  if (lane == 0) { redS[wave] = s; redQ[wave] = q; }
  __syncthreads();
  float tot = redS[0] + redS[1] + redS[2] + redS[3];
  float totq = redQ[0] + redQ[1] + redQ[2] + redQ[3];
  float mu = tot * (1.f / 512.f);
  float var = totq * (1.f / 512.f) - mu * mu;
  float rs = rsqrtf(var + 1e-3f);
  y[tid]       = (v0 - mu) * rs * gamma[tid] + beta[tid];
  y[tid + 256] = (v1 - mu) * rs * gamma[tid + 256] + beta[tid + 256];
  __syncthreads();
  float acc = b2[tid];
  for (int k = 0; k < 512; k++) acc += y[k] * W2[k * 256 + tid];
  float pv = fmaxf(acc, 0.f) * W3[tid];
#pragma unroll
  for (int o = 32; o; o >>= 1) pv += __shfl_down(pv, o);
  if (lane == 0) redP[wave] = pv;
  __syncthreads();
  if (tid == 0) out[b] = redP[0] + redP[1] + redP[2] + redP[3] + b3[0];
}

extern "C" void kernel_launch(void* const* d_in, const int* in_sizes, int n_in,
                              void* d_out, int out_size, void* d_ws, size_t ws_size,
                              hipStream_t stream)
{
  (void)in_sizes; (void)n_in; (void)out_size; (void)ws_size;
  const float* x    = (const float*)d_in[0];
  const float* W1   = (const float*)d_in[1];
  const float* b1   = (const float*)d_in[2];
  const float* Wx1  = (const float*)d_in[3];
  const float* Wh1  = (const float*)d_in[4];
  const float* bl1  = (const float*)d_in[5];
  const float* Wx2  = (const float*)d_in[6];
  const float* Wh2  = (const float*)d_in[7];
  const float* bl2  = (const float*)d_in[8];
  const float* gam  = (const float*)d_in[9];
  const float* bet  = (const float*)d_in[10];
  const float* W2   = (const float*)d_in[11];
  const float* b2   = (const float*)d_in[12];
  const float* W3   = (const float*)d_in[13];
  const float* b3   = (const float*)d_in[14];

  char* p = (char*)d_ws;
  const size_t MB = 1024 * 1024;
  __hip_bfloat16* wx1t = (__hip_bfloat16*)(p + 0 * MB);
  __hip_bfloat16* wh1t = (__hip_bfloat16*)(p + 2 * MB);
  __hip_bfloat16* wx2t = (__hip_bfloat16*)(p + 4 * MB);
  __hip_bfloat16* wh2t = (__hip_bfloat16*)(p + 6 * MB);
  __hip_bfloat16* w1b  = (__hip_bfloat16*)(p + 8 * MB);
  __hip_bfloat16* h0   = (__hip_bfloat16*)(p + 9 * MB);   // 32 MB
  __hip_bfloat16* seq  = (__hip_bfloat16*)(p + 41 * MB);  // 32 MB
  char* st = p + 73 * MB;
  __hip_bfloat16* h1a = (__hip_bfloat16*)st;
  __hip_bfloat16* h1b = h1a + B_ * H_;
  __hip_bfloat16* h2a = h1b + B_ * H_;
  __hip_bfloat16* h2b = h2a + B_ * H_;
  float* c1  = (float*)(st + 512 * 1024);
  float* c2  = c1 + B_ * H_;
  float* h2f = c2 + B_ * H_;
  int nzero = (int)((1024 * 1024) / 4);  // zero h bufs (512KB) + c1/c2 (512KB)

  transpose_cast_k<<<dim3(32, 8, 4), 256, 0, stream>>>(Wx1, Wh1, Wx2, Wh2, wx1t);
  prep_misc_k<<<256, 256, 0, stream>>>(W1, w1b, (float*)st, nzero);
  dense1_k<<<1024, 512, 0, stream>>>(x, w1b, b1, h0);

  for (int t = 0; t < T_; t++) {
    __hip_bfloat16* hin  = (t & 1) ? h1b : h1a;
    __hip_bfloat16* hout = (t & 1) ? h1a : h1b;
    lstm_step_k<<<64, 256, 0, stream>>>(hin, h0, wh1t, wx1t, bl1, c1, hout, seq, nullptr, t);
  }
  for (int t = 0; t < T_; t++) {
    __hip_bfloat16* hin  = (t & 1) ? h2b : h2a;
    __hip_bfloat16* hout = (t & 1) ? h2a : h2b;
    lstm_step_k<<<64, 256, 0, stream>>>(hin, seq, wh2t, wx2t, bl2, c2, hout, nullptr, h2f, t);
  }
  final_k<<<128, 256, 0, stream>>>(h2f, gam, bet, W2, b2, W3, b3, (float*)d_out);
}